// Round 5
// baseline (421.584 us; speedup 1.0000x reference)
//
#include <hip/hip_runtime.h>

// AGCRNCell on gfx950.  B=32, N=2048, C=66, CHEB_K=3, F=2112 (T padded to 2176 rows).
// R5: GEMM K-loop restructured -- single-wave workgroups (64 thr), NO barriers,
//     explicit LDS double-buffer with s_waitcnt vmcnt(16) (next-buf loads stay in
//     flight across the wait; the R1-R4 plateau was the vmcnt(0)+s_barrier drain).
//     64x64 tile, BK=64, 32KB LDS -> 5 blocks/CU, all 1088 big-GEMM blocks resident.
//     XCD swizzle: id%8 picks a group of 4 m-strips -> per-XCD L2 holds its A strips.

typedef __bf16 bf16x8 __attribute__((ext_vector_type(8)));
typedef __bf16 bf16x4 __attribute__((ext_vector_type(4)));
typedef float  f32x4  __attribute__((ext_vector_type(4)));

#define GLB(p) ((__attribute__((address_space(1))) void*)(void*)(p))
#define LDS(p) ((__attribute__((address_space(3))) void*)(p))

// ---------------- supports: S[n][m] = softmax_m(relu(E[n]·E[m])) ----------------
__global__ void supports_kernel(const float* __restrict__ E, __bf16* __restrict__ S) {
    const int n = blockIdx.x;
    const int t = threadIdx.x;            // 256
    const int l = t & 63, w = t >> 6;
    float en[10];
#pragma unroll
    for (int i = 0; i < 10; ++i) en[i] = E[n * 10 + i];
    float vals[8];
    float mx = 0.f;
#pragma unroll
    for (int q = 0; q < 8; ++q) {
        const int m = q * 256 + t;
        const float* em = E + (size_t)m * 10;
        float d = 0.f;
#pragma unroll
        for (int i = 0; i < 10; ++i) d += en[i] * em[i];
        d = fmaxf(d, 0.f);
        vals[q] = d;
        mx = fmaxf(mx, d);
    }
#pragma unroll
    for (int off = 32; off; off >>= 1) mx = fmaxf(mx, __shfl_xor(mx, off));
    __shared__ float sm[4], ss[4];
    if (l == 0) sm[w] = mx;
    __syncthreads();
    mx = fmaxf(fmaxf(sm[0], sm[1]), fmaxf(sm[2], sm[3]));
    float sum = 0.f;
#pragma unroll
    for (int q = 0; q < 8; ++q) { vals[q] = __expf(vals[q] - mx); sum += vals[q]; }
#pragma unroll
    for (int off = 32; off; off >>= 1) sum += __shfl_xor(sum, off);
    if (l == 0) ss[w] = sum;
    __syncthreads();
    sum = ss[0] + ss[1] + ss[2] + ss[3];
    const float inv = 1.f / sum;
#pragma unroll
    for (int q = 0; q < 8; ++q) S[(size_t)n * 2048 + q * 256 + t] = (__bf16)(vals[q] * inv);
}

// ---------------- zero pad rows f in [2112,2176) of T0 ----------------
__global__ void zero_pad(__bf16* __restrict__ Tpad) {
    const int id = blockIdx.x * 256 + threadIdx.x;   // 64*2048/8 = 16384 tasks
    bf16x8 z;
#pragma unroll
    for (int j = 0; j < 8; ++j) z[j] = (__bf16)0.f;
    *(bf16x8*)&Tpad[(size_t)id * 8] = z;
}

// ---------------- build T via LDS transpose: T[f=b*66+c][n], coalesced both sides ----
__global__ __launch_bounds__(256, 2)
void build_t2(const float* __restrict__ x, const float* __restrict__ st,
              const __bf16* __restrict__ zr, __bf16* __restrict__ T) {
    __shared__ float Ls[66 * 129];       // 34 KB
    const int b  = blockIdx.x >> 4;
    const int n0 = (blockIdx.x & 15) << 7;
    const int t = threadIdx.x;
    const size_t mb = (size_t)b * 2048 + n0;
    if (t < 128) {
        const float2 v = *(const float2*)&x[(mb + t) * 2];
        Ls[t] = v.x;
        Ls[129 + t] = v.y;
    }
#pragma unroll
    for (int r = 0; r < 8; ++r) {        // 128 rows x 16 col-quads
        const int task = r * 256 + t;
        const int q = task & 15, n = task >> 4;
        f32x4 v = *(const f32x4*)&st[(mb + n) * 64 + q * 4];
        if (zr) {
            const bf16x4 z = *(const bf16x4*)&zr[(mb + n) * 128 + q * 4];
#pragma unroll
            for (int j = 0; j < 4; ++j) v[j] *= (float)z[j];
        }
        const int base = (2 + q * 4) * 129 + n;
#pragma unroll
        for (int j = 0; j < 4; ++j) Ls[base + j * 129] = v[j];
    }
    __syncthreads();
#pragma unroll
    for (int r = 0; r < 5; ++r) {        // 66 c x 16 segs = 1056 tasks
        const int task = r * 256 + t;
        if (task < 1056) {
            const int c = task >> 4, seg = task & 15;
            const float* src = &Ls[c * 129 + seg * 8];
            bf16x8 o;
#pragma unroll
            for (int j = 0; j < 8; ++j) o[j] = (__bf16)src[j];
            *(bf16x8*)&T[(size_t)(b * 66 + c) * 2048 + n0 + seg * 8] = o;
        }
    }
}

// ---------------- transpose T-layout -> G[m=(b,n)][k], k padded to 256 ----------------
__global__ __launch_bounds__(256, 2)
void transpose_g(const __bf16* __restrict__ T0, const __bf16* __restrict__ T1,
                 const __bf16* __restrict__ T2, __bf16* __restrict__ G) {
    __shared__ __bf16 Ls[128 * 256];     // 64 KB
    const int b  = blockIdx.x >> 4;      // 0..31
    const int n0 = (blockIdx.x & 15) << 7;
    const int t = threadIdx.x;
#pragma unroll
    for (int r = 0; r < 16; ++r) {       // 256 k x 16 segs
        const int task = r * 256 + t;
        const int k = task >> 4, seg = task & 15;
        bf16x8 v;
        if (k < 198) {
            const __bf16* T; int c;
            if (k < 66)       { T = T0; c = k; }
            else if (k < 132) { T = T1; c = k - 66; }
            else              { T = T2; c = k - 132; }
            v = *(const bf16x8*)&T[(size_t)(b * 66 + c) * 2048 + n0 + seg * 8];
        } else {
#pragma unroll
            for (int j = 0; j < 8; ++j) v[j] = (__bf16)0.f;
        }
        const int base = seg * 8 * 256 + (((k >> 3) ^ seg) << 3) + (k & 7);
#pragma unroll
        for (int j = 0; j < 8; ++j) Ls[base + j * 256] = v[j];
    }
    __syncthreads();
#pragma unroll
    for (int r = 0; r < 16; ++r) {       // 128 m x 32 chunks
        const int task = r * 256 + t;
        const int m = task >> 5, c8 = task & 31;
        bf16x8 w = *(const bf16x8*)&Ls[m * 256 + ((c8 ^ (m >> 3)) << 3)];
        *(bf16x8*)&G[(size_t)(b * 2048 + n0 + m) * 256 + c8 * 8] = w;
    }
}

// ---------------- build W^T padded: WT[o][k] (128x256) ----------------
__global__ void build_wt(const float* __restrict__ W, __bf16* __restrict__ WT, int Nout) {
    const int id = blockIdx.x * 256 + threadIdx.x;   // 128*256
    const int o = id >> 8, k = id & 255;
    WT[id] = (o < Nout && k < 198) ? (__bf16)W[(size_t)k * Nout + o] : (__bf16)0.f;
}

// ---------------- GEMM: out[M][C] = A[M][K] @ B, B given as Bt[C][K] ----------------
// Single wave (64 thr) per block, 64(m) x 64(c) tile, BK=64, double-buffered LDS,
// NO barriers: stage next buf -> s_waitcnt vmcnt(16) -> compute current buf.
// XOR-granule swizzle (slot = g ^ (row&7)) -> conflict-free ds_read_b128; staging
// permutes the per-lane global source (LDS dest stays wave-uniform + lane*16).
// swz=1: id -> m_tile=(id%8)*4+((id>>3)&3), c_tile=id>>5  (pins 4 m-strips per XCD).
// epi: 0 outT[c][m] = bf16(acc)            (ld 2048)
//      1 outT[c][m] = bf16(2*acc - subT[c][m])
//      2 zrO[m*128+c] = bf16(sigmoid(acc + bias[c]))
//      3 (c<64) outF[m*64+c] = r*state + (1-r)*tanh(acc+bias[c]), r = zrI[m*128+64+c]
__global__ __launch_bounds__(64, 2)
void gemm_dw(const __bf16* __restrict__ A, int lda,
             const __bf16* __restrict__ Bt, int ldb,
             int K, int epi, int swz,
             __bf16* __restrict__ outT, const __bf16* __restrict__ subT,
             float* __restrict__ outF, const float* __restrict__ bias,
             __bf16* __restrict__ zrO, const __bf16* __restrict__ zrI,
             const float* __restrict__ state) {
    __shared__ __align__(16) __bf16 As[2][64 * 64];   // 16 KB
    __shared__ __align__(16) __bf16 Bs[2][64 * 64];   // 16 KB
    int mt, ct;
    if (swz) {
        const int id = blockIdx.x;
        mt = (id & 7) * 4 + ((id >> 3) & 3);
        ct = id >> 5;
    } else {
        mt = blockIdx.x;
        ct = blockIdx.y;
    }
    const int m0 = mt * 64, c0 = ct * 64;
    const int l = threadIdx.x;           // 64
    const int lm = l & 15, kq = l >> 4, lm7 = lm & 7;
    const int sr = l >> 3;               // staging row-within-8
    const int gsw = (l & 7) ^ sr;        // swizzled source granule

    f32x4 acc[4][4];
#pragma unroll
    for (int i = 0; i < 4; ++i)
#pragma unroll
        for (int j = 0; j < 4; ++j) acc[i][j] = (f32x4)0.f;

    const __bf16* Asrc = A  + (size_t)(m0 + sr) * lda + gsw * 8;
    const __bf16* Bsrc = Bt + (size_t)(c0 + sr) * ldb + gsw * 8;
    const int dst = l * 8;               // lane-linear LDS dest (elements)

    auto stage = [&](int buf, int k0) {
#pragma unroll
        for (int q = 0; q < 8; ++q)
            __builtin_amdgcn_global_load_lds(GLB(Asrc + (size_t)q * 8 * lda + k0),
                                             LDS(&As[buf][q * 512 + dst]), 16, 0, 0);
#pragma unroll
        for (int q = 0; q < 8; ++q)
            __builtin_amdgcn_global_load_lds(GLB(Bsrc + (size_t)q * 8 * ldb + k0),
                                             LDS(&Bs[buf][q * 512 + dst]), 16, 0, 0);
    };
    auto compute = [&](int buf) {
#pragma unroll
        for (int ks = 0; ks < 2; ++ks) {
            const int ga = (((ks << 2) | kq) ^ lm7) << 3;
            bf16x8 af[4], bfr[4];
#pragma unroll
            for (int i = 0; i < 4; ++i)
                af[i] = *(const bf16x8*)&As[buf][(i * 16 + lm) * 64 + ga];
#pragma unroll
            for (int j = 0; j < 4; ++j)
                bfr[j] = *(const bf16x8*)&Bs[buf][(j * 16 + lm) * 64 + ga];
#pragma unroll
            for (int i = 0; i < 4; ++i)
#pragma unroll
                for (int j = 0; j < 4; ++j)
                    acc[i][j] = __builtin_amdgcn_mfma_f32_16x16x32_bf16(af[i], bfr[j], acc[i][j], 0, 0, 0);
        }
    };

    stage(0, 0);
    int buf = 0;
    for (int k0 = 64; k0 < K; k0 += 64) {
        stage(buf ^ 1, k0);
        __builtin_amdgcn_sched_barrier(0);
        __builtin_amdgcn_s_waitcnt(0x4F70);   // vmcnt(16): current buf's 16 loads done
        __builtin_amdgcn_sched_barrier(0);
        compute(buf);
        __builtin_amdgcn_sched_barrier(0);
        buf ^= 1;
    }
    __builtin_amdgcn_sched_barrier(0);
    __builtin_amdgcn_s_waitcnt(0x0F70);       // vmcnt(0)
    __builtin_amdgcn_sched_barrier(0);
    compute(buf);

    // epilogue: C row = m (quad*4+reg), col = lane&15  [verified m89 layout]
    const int rb0 = m0 + kq * 4;
    const int cb0 = c0 + lm;
#pragma unroll
    for (int i = 0; i < 4; ++i) {
        const int rbase = rb0 + i * 16;
#pragma unroll
        for (int j = 0; j < 4; ++j) {
            const int c = cb0 + j * 16;
            f32x4 v = acc[i][j];
            if (epi == 0) {
                bf16x4 pk;
#pragma unroll
                for (int r = 0; r < 4; ++r) pk[r] = (__bf16)v[r];
                *(bf16x4*)&outT[(size_t)c * 2048 + rbase] = pk;
            } else if (epi == 1) {
                bf16x4 s = *(const bf16x4*)&subT[(size_t)c * 2048 + rbase];
                bf16x4 pk;
#pragma unroll
                for (int r = 0; r < 4; ++r) pk[r] = (__bf16)(2.f * v[r] - (float)s[r]);
                *(bf16x4*)&outT[(size_t)c * 2048 + rbase] = pk;
            } else if (epi == 2) {
                const float bb = bias[c];
#pragma unroll
                for (int r = 0; r < 4; ++r) {
                    float xx = fminf(fmaxf(v[r] + bb, -30.f), 30.f);
                    zrO[(size_t)(rbase + r) * 128 + c] = (__bf16)(1.f / (1.f + __expf(-xx)));
                }
            } else {
                if (c < 64) {
                    const float bb = bias[c];
#pragma unroll
                    for (int r = 0; r < 4; ++r) {
                        const int m = rbase + r;
                        float xx = fminf(fmaxf(v[r] + bb, -15.f), 15.f);
                        float e = __expf(2.f * xx);
                        float hc = (e - 1.f) / (e + 1.f);
                        float rr = (float)zrI[(size_t)m * 128 + 64 + c];
                        float s = state[(size_t)m * 64 + c];
                        outF[(size_t)m * 64 + c] = rr * s + (1.f - rr) * hc;
                    }
                }
            }
        }
    }
}

extern "C" void kernel_launch(void* const* d_in, const int* in_sizes, int n_in,
                              void* d_out, int out_size, void* d_ws, size_t ws_size,
                              hipStream_t stream) {
    (void)in_sizes; (void)n_in; (void)out_size; (void)ws_size;
    const float* x  = (const float*)d_in[0];
    const float* st = (const float*)d_in[1];
    const float* E  = (const float*)d_in[2];
    const float* Wg = (const float*)d_in[3];
    const float* bg = (const float*)d_in[4];
    const float* Wu = (const float*)d_in[5];
    const float* bu = (const float*)d_in[6];
    float* out = (float*)d_out;

    char* p = (char*)d_ws;
    __bf16* S   = (__bf16*)p; p += (size_t)2048 * 2048 * 2;   // 8.4 MB
    __bf16* T0  = (__bf16*)p; p += (size_t)2176 * 2048 * 2;   // 8.9 MB
    __bf16* T1  = (__bf16*)p; p += (size_t)2176 * 2048 * 2;
    __bf16* T2  = (__bf16*)p; p += (size_t)2176 * 2048 * 2;
    __bf16* G   = (__bf16*)p; p += (size_t)65536 * 256 * 2;   // 33.6 MB
    __bf16* ZR  = (__bf16*)p; p += (size_t)65536 * 128 * 2;   // 16.8 MB
    __bf16* WTg = (__bf16*)p; p += 128 * 256 * 2;
    __bf16* WTu = (__bf16*)p; p += 128 * 256 * 2;             // ~86 MB

    build_wt<<<128, 256, 0, stream>>>(Wg, WTg, 128);
    build_wt<<<128, 256, 0, stream>>>(Wu, WTu, 64);
    zero_pad<<<64, 256, 0, stream>>>(T0 + (size_t)2112 * 2048);
    supports_kernel<<<2048, 256, 0, stream>>>(E, S);

    // gate phase
    build_t2<<<512, 256, 0, stream>>>(x, st, nullptr, T0);
    gemm_dw<<<1088, 64, 0, stream>>>(S, 2048, T0, 2048, 2048, 0, 1, T1, nullptr, nullptr, nullptr, nullptr, nullptr, nullptr);
    gemm_dw<<<1088, 64, 0, stream>>>(S, 2048, T1, 2048, 2048, 1, 1, T2, T0, nullptr, nullptr, nullptr, nullptr, nullptr);
    transpose_g<<<512, 256, 0, stream>>>(T0, T1, T2, G);
    gemm_dw<<<dim3(1024, 2), 64, 0, stream>>>(G, 256, WTg, 256, 256, 2, 0, nullptr, nullptr, nullptr, bg, ZR, nullptr, nullptr);

    // update phase
    build_t2<<<512, 256, 0, stream>>>(x, st, ZR, T0);
    gemm_dw<<<1088, 64, 0, stream>>>(S, 2048, T0, 2048, 2048, 0, 1, T1, nullptr, nullptr, nullptr, nullptr, nullptr, nullptr);
    gemm_dw<<<1088, 64, 0, stream>>>(S, 2048, T1, 2048, 2048, 1, 1, T2, T0, nullptr, nullptr, nullptr, nullptr, nullptr);
    transpose_g<<<512, 256, 0, stream>>>(T0, T1, T2, G);
    gemm_dw<<<dim3(1024, 1), 64, 0, stream>>>(G, 256, WTu, 256, 256, 3, 0, nullptr, nullptr, out, bu, nullptr, ZR, st);
}

// Round 6
// 278.581 us; speedup vs baseline: 1.5133x; 1.5133x over previous
//
#include <hip/hip_runtime.h>

// AGCRNCell on gfx950.  B=32, N=2048, C=66, CHEB_K=3, F=2112 (= 33*64, no pad).
// R6: pipelined GEMM -- 4-wave blocks, 128m x 64c tile, BK=64, LDS double-buffer,
//     RAW s_barrier + manual s_waitcnt vmcnt(6): each wave waits only its OWN
//     current-buffer global_load_lds; next-buffer prefetch stays in flight across
//     the barrier (the R1-R5 plateau was the vmcnt(0) drain __syncthreads emits).
//     R5 lesson: single-wave blocks (5 waves/CU) have no TLP -- regressed to 9% Mfma.

typedef __bf16 bf16x8 __attribute__((ext_vector_type(8)));
typedef __bf16 bf16x4 __attribute__((ext_vector_type(4)));
typedef float  f32x4  __attribute__((ext_vector_type(4)));

#define GLB(p) ((__attribute__((address_space(1))) void*)(void*)(p))
#define LDS(p) ((__attribute__((address_space(3))) void*)(p))

// ---------------- supports: S[n][m] = softmax_m(relu(E[n]·E[m])) ----------------
__global__ void supports_kernel(const float* __restrict__ E, __bf16* __restrict__ S) {
    const int n = blockIdx.x;
    const int t = threadIdx.x;            // 256
    const int l = t & 63, w = t >> 6;
    float en[10];
#pragma unroll
    for (int i = 0; i < 10; ++i) en[i] = E[n * 10 + i];
    float vals[8];
    float mx = 0.f;
#pragma unroll
    for (int q = 0; q < 8; ++q) {
        const int m = q * 256 + t;
        const float* em = E + (size_t)m * 10;
        float d = 0.f;
#pragma unroll
        for (int i = 0; i < 10; ++i) d += en[i] * em[i];
        d = fmaxf(d, 0.f);
        vals[q] = d;
        mx = fmaxf(mx, d);
    }
#pragma unroll
    for (int off = 32; off; off >>= 1) mx = fmaxf(mx, __shfl_xor(mx, off));
    __shared__ float sm[4], ss[4];
    if (l == 0) sm[w] = mx;
    __syncthreads();
    mx = fmaxf(fmaxf(sm[0], sm[1]), fmaxf(sm[2], sm[3]));
    float sum = 0.f;
#pragma unroll
    for (int q = 0; q < 8; ++q) { vals[q] = __expf(vals[q] - mx); sum += vals[q]; }
#pragma unroll
    for (int off = 32; off; off >>= 1) sum += __shfl_xor(sum, off);
    if (l == 0) ss[w] = sum;
    __syncthreads();
    sum = ss[0] + ss[1] + ss[2] + ss[3];
    const float inv = 1.f / sum;
#pragma unroll
    for (int q = 0; q < 8; ++q) S[(size_t)n * 2048 + q * 256 + t] = (__bf16)(vals[q] * inv);
}

// ---------------- build T via LDS transpose: T[f=b*66+c][n], coalesced both sides ----
__global__ __launch_bounds__(256, 2)
void build_t2(const float* __restrict__ x, const float* __restrict__ st,
              const __bf16* __restrict__ zr, __bf16* __restrict__ T) {
    __shared__ float Ls[66 * 129];       // 34 KB
    const int b  = blockIdx.x >> 4;
    const int n0 = (blockIdx.x & 15) << 7;
    const int t = threadIdx.x;
    const size_t mb = (size_t)b * 2048 + n0;
    if (t < 128) {
        const float2 v = *(const float2*)&x[(mb + t) * 2];
        Ls[t] = v.x;
        Ls[129 + t] = v.y;
    }
#pragma unroll
    for (int r = 0; r < 8; ++r) {        // 128 rows x 16 col-quads
        const int task = r * 256 + t;
        const int q = task & 15, n = task >> 4;
        f32x4 v = *(const f32x4*)&st[(mb + n) * 64 + q * 4];
        if (zr) {
            const bf16x4 z = *(const bf16x4*)&zr[(mb + n) * 128 + q * 4];
#pragma unroll
            for (int j = 0; j < 4; ++j) v[j] *= (float)z[j];
        }
        const int base = (2 + q * 4) * 129 + n;
#pragma unroll
        for (int j = 0; j < 4; ++j) Ls[base + j * 129] = v[j];
    }
    __syncthreads();
#pragma unroll
    for (int r = 0; r < 5; ++r) {        // 66 c x 16 segs = 1056 tasks
        const int task = r * 256 + t;
        if (task < 1056) {
            const int c = task >> 4, seg = task & 15;
            const float* src = &Ls[c * 129 + seg * 8];
            bf16x8 o;
#pragma unroll
            for (int j = 0; j < 8; ++j) o[j] = (__bf16)src[j];
            *(bf16x8*)&T[(size_t)(b * 66 + c) * 2048 + n0 + seg * 8] = o;
        }
    }
}

// ---------------- transpose T-layout -> G[m=(b,n)][k], k padded to 256 ----------------
__global__ __launch_bounds__(256, 2)
void transpose_g(const __bf16* __restrict__ T0, const __bf16* __restrict__ T1,
                 const __bf16* __restrict__ T2, __bf16* __restrict__ G) {
    __shared__ __bf16 Ls[128 * 256];     // 64 KB
    const int b  = blockIdx.x >> 4;      // 0..31
    const int n0 = (blockIdx.x & 15) << 7;
    const int t = threadIdx.x;
#pragma unroll
    for (int r = 0; r < 16; ++r) {       // 256 k x 16 segs
        const int task = r * 256 + t;
        const int k = task >> 4, seg = task & 15;
        bf16x8 v;
        if (k < 198) {
            const __bf16* T; int c;
            if (k < 66)       { T = T0; c = k; }
            else if (k < 132) { T = T1; c = k - 66; }
            else              { T = T2; c = k - 132; }
            v = *(const bf16x8*)&T[(size_t)(b * 66 + c) * 2048 + n0 + seg * 8];
        } else {
#pragma unroll
            for (int j = 0; j < 8; ++j) v[j] = (__bf16)0.f;
        }
        const int base = seg * 8 * 256 + (((k >> 3) ^ seg) << 3) + (k & 7);
#pragma unroll
        for (int j = 0; j < 8; ++j) Ls[base + j * 256] = v[j];
    }
    __syncthreads();
#pragma unroll
    for (int r = 0; r < 16; ++r) {       // 128 m x 32 chunks
        const int task = r * 256 + t;
        const int m = task >> 5, c8 = task & 31;
        bf16x8 w = *(const bf16x8*)&Ls[m * 256 + ((c8 ^ (m >> 3)) << 3)];
        *(bf16x8*)&G[(size_t)(b * 2048 + n0 + m) * 256 + c8 * 8] = w;
    }
}

// ---------------- build W^T padded: WT[o][k] (128x256) ----------------
__global__ void build_wt(const float* __restrict__ W, __bf16* __restrict__ WT, int Nout) {
    const int id = blockIdx.x * 256 + threadIdx.x;   // 128*256
    const int o = id >> 8, k = id & 255;
    WT[id] = (o < Nout && k < 198) ? (__bf16)W[(size_t)k * Nout + o] : (__bf16)0.f;
}

// ---------------- pipelined GEMM: out[M][C] = A[M][K] @ Bt[C][K]^T ----------------
// 256 thr = 4 waves (2m x 2c), tile 128m x 64c, wave-tile 64x32 (4x2 frags), BK=64.
// Double-buffered LDS; per iter: stage next (6 global_load_lds/thread) ->
// s_waitcnt vmcnt(6) (own cur loads done, prefetch in flight) -> raw s_barrier ->
// compute -> raw s_barrier. XOR-granule swizzle: conflict-free ds_read_b128.
// swz=1: mt = id&15 (same mt -> same XCD under round-robin), ct = id>>4.
// epi: 0 outT[c][m]=bf16(acc); 1 outT[c][m]=bf16(2*acc-subT[c][m]);
//      2 zrO[m*128+c]=bf16(sigmoid(acc+bias[c]));
//      3 (c<64) outF[m*64+c]=r*state+(1-r)*tanh(acc+bias[c]), r=zrI[m*128+64+c]
__global__ __launch_bounds__(256, 3)
void gemm_pipe(const __bf16* __restrict__ A, int lda,
               const __bf16* __restrict__ Bt, int ldb,
               int K, int epi, int swz,
               __bf16* __restrict__ outT, const __bf16* __restrict__ subT,
               float* __restrict__ outF, const float* __restrict__ bias,
               __bf16* __restrict__ zrO, const __bf16* __restrict__ zrI,
               const float* __restrict__ state) {
    __shared__ __align__(16) __bf16 As[2][128 * 64];   // 32 KB
    __shared__ __align__(16) __bf16 Bs[2][64 * 64];    // 16 KB
    int mt, ct;
    if (swz) { mt = blockIdx.x & 15; ct = blockIdx.x >> 4; }
    else     { mt = blockIdx.x;      ct = blockIdx.y; }
    const int m0 = mt * 128, c0 = ct * 64;
    const int t = threadIdx.x;
    const int l = t & 63, w = t >> 6;
    const int wr = w >> 1, wc = w & 1;
    const int lm = l & 15, kq = l >> 4, lm7 = lm & 7;
    const int sr = l >> 3;               // row-within-chunk
    const int gsw = (l & 7) ^ sr;        // swizzled source granule

    f32x4 acc[4][2];
#pragma unroll
    for (int i = 0; i < 4; ++i)
#pragma unroll
        for (int j = 0; j < 2; ++j) acc[i][j] = (f32x4)0.f;

    // staging: A chunks ci=q*4+w (q=0..3) of 8 rows; B chunks ci=q*4+w (q=0..1)
    const __bf16* Asrc = A  + (size_t)(m0 + w * 8 + sr) * lda + gsw * 8;
    const __bf16* Bsrc = Bt + (size_t)(c0 + w * 8 + sr) * ldb + gsw * 8;
    const int dstA = w * 512 + l * 8;
    const int dstB = w * 512 + l * 8;

    auto stage = [&](int buf, int k0) {
#pragma unroll
        for (int q = 0; q < 4; ++q)
            __builtin_amdgcn_global_load_lds(GLB(Asrc + (size_t)q * 32 * lda + k0),
                                             LDS(&As[buf][q * 2048 + dstA]), 16, 0, 0);
#pragma unroll
        for (int q = 0; q < 2; ++q)
            __builtin_amdgcn_global_load_lds(GLB(Bsrc + (size_t)q * 32 * ldb + k0),
                                             LDS(&Bs[buf][q * 2048 + dstB]), 16, 0, 0);
    };
    auto compute = [&](int buf) {
#pragma unroll
        for (int ks = 0; ks < 2; ++ks) {
            const int ga = (((ks << 2) | kq) ^ lm7) << 3;
            bf16x8 af[4], bfr[2];
#pragma unroll
            for (int i = 0; i < 4; ++i)
                af[i] = *(const bf16x8*)&As[buf][(wr * 64 + i * 16 + lm) * 64 + ga];
#pragma unroll
            for (int j = 0; j < 2; ++j)
                bfr[j] = *(const bf16x8*)&Bs[buf][(wc * 32 + j * 16 + lm) * 64 + ga];
#pragma unroll
            for (int i = 0; i < 4; ++i)
#pragma unroll
                for (int j = 0; j < 2; ++j)
                    acc[i][j] = __builtin_amdgcn_mfma_f32_16x16x32_bf16(af[i], bfr[j], acc[i][j], 0, 0, 0);
        }
    };

    stage(0, 0);
    const int iters = K >> 6;            // even (32 big / 4 W)
    for (int i = 0; i + 2 <= iters; i += 2) {
        stage(1, (i + 1) << 6);
        __builtin_amdgcn_sched_barrier(0);
        __builtin_amdgcn_s_waitcnt(0x0F76);      // vmcnt(6): own buf0 loads done
        __builtin_amdgcn_s_barrier();
        __builtin_amdgcn_sched_barrier(0);
        compute(0);
        __builtin_amdgcn_sched_barrier(0);
        __builtin_amdgcn_s_barrier();            // buf0 free for restage
        __builtin_amdgcn_sched_barrier(0);
        if (i + 2 < iters) {
            stage(0, (i + 2) << 6);
            __builtin_amdgcn_sched_barrier(0);
            __builtin_amdgcn_s_waitcnt(0x0F76);  // vmcnt(6): own buf1 loads done
        } else {
            __builtin_amdgcn_s_waitcnt(0x0F70);  // vmcnt(0)
        }
        __builtin_amdgcn_s_barrier();
        __builtin_amdgcn_sched_barrier(0);
        compute(1);
        __builtin_amdgcn_sched_barrier(0);
        if (i + 4 <= iters) {
            __builtin_amdgcn_s_barrier();        // buf1 free for restage
            __builtin_amdgcn_sched_barrier(0);
        }
    }

    // epilogue: C row = m (quad*4+reg), col = lane&15  [verified m89 layout]
    const int rb0 = m0 + wr * 64 + kq * 4;
    const int cb0 = c0 + wc * 32 + lm;
#pragma unroll
    for (int i = 0; i < 4; ++i) {
        const int rbase = rb0 + i * 16;
#pragma unroll
        for (int j = 0; j < 2; ++j) {
            const int c = cb0 + j * 16;
            f32x4 v = acc[i][j];
            if (epi == 0) {
                bf16x4 pk;
#pragma unroll
                for (int r = 0; r < 4; ++r) pk[r] = (__bf16)v[r];
                *(bf16x4*)&outT[(size_t)c * 2048 + rbase] = pk;
            } else if (epi == 1) {
                bf16x4 s = *(const bf16x4*)&subT[(size_t)c * 2048 + rbase];
                bf16x4 pk;
#pragma unroll
                for (int r = 0; r < 4; ++r) pk[r] = (__bf16)(2.f * v[r] - (float)s[r]);
                *(bf16x4*)&outT[(size_t)c * 2048 + rbase] = pk;
            } else if (epi == 2) {
                const float bb = bias[c];
#pragma unroll
                for (int r = 0; r < 4; ++r) {
                    float xx = fminf(fmaxf(v[r] + bb, -30.f), 30.f);
                    zrO[(size_t)(rbase + r) * 128 + c] = (__bf16)(1.f / (1.f + __expf(-xx)));
                }
            } else {
                if (c < 64) {
                    const float bb = bias[c];
#pragma unroll
                    for (int r = 0; r < 4; ++r) {
                        const int m = rbase + r;
                        float xx = fminf(fmaxf(v[r] + bb, -15.f), 15.f);
                        float e = __expf(2.f * xx);
                        float hc = (e - 1.f) / (e + 1.f);
                        float rr = (float)zrI[(size_t)m * 128 + 64 + c];
                        float s = state[(size_t)m * 64 + c];
                        outF[(size_t)m * 64 + c] = rr * s + (1.f - rr) * hc;
                    }
                }
            }
        }
    }
}

extern "C" void kernel_launch(void* const* d_in, const int* in_sizes, int n_in,
                              void* d_out, int out_size, void* d_ws, size_t ws_size,
                              hipStream_t stream) {
    (void)in_sizes; (void)n_in; (void)out_size; (void)ws_size;
    const float* x  = (const float*)d_in[0];
    const float* st = (const float*)d_in[1];
    const float* E  = (const float*)d_in[2];
    const float* Wg = (const float*)d_in[3];
    const float* bg = (const float*)d_in[4];
    const float* Wu = (const float*)d_in[5];
    const float* bu = (const float*)d_in[6];
    float* out = (float*)d_out;

    char* p = (char*)d_ws;
    __bf16* S   = (__bf16*)p; p += (size_t)2048 * 2048 * 2;   // 8.4 MB
    __bf16* T0  = (__bf16*)p; p += (size_t)2112 * 2048 * 2;   // 8.65 MB
    __bf16* T1  = (__bf16*)p; p += (size_t)2112 * 2048 * 2;
    __bf16* T2  = (__bf16*)p; p += (size_t)2112 * 2048 * 2;
    __bf16* G   = (__bf16*)p; p += (size_t)65536 * 256 * 2;   // 33.6 MB
    __bf16* ZR  = (__bf16*)p; p += (size_t)65536 * 128 * 2;   // 16.8 MB
    __bf16* WTg = (__bf16*)p; p += 128 * 256 * 2;
    __bf16* WTu = (__bf16*)p; p += 128 * 256 * 2;             // ~84 MB

    build_wt<<<128, 256, 0, stream>>>(Wg, WTg, 128);
    build_wt<<<128, 256, 0, stream>>>(Wu, WTu, 64);
    supports_kernel<<<2048, 256, 0, stream>>>(E, S);

    // gate phase
    build_t2<<<512, 256, 0, stream>>>(x, st, nullptr, T0);
    gemm_pipe<<<528, 256, 0, stream>>>(S, 2048, T0, 2048, 2048, 0, 1, T1, nullptr, nullptr, nullptr, nullptr, nullptr, nullptr);
    gemm_pipe<<<528, 256, 0, stream>>>(S, 2048, T1, 2048, 2048, 1, 1, T2, T0, nullptr, nullptr, nullptr, nullptr, nullptr);
    transpose_g<<<512, 256, 0, stream>>>(T0, T1, T2, G);
    gemm_pipe<<<dim3(512, 2), 256, 0, stream>>>(G, 256, WTg, 256, 256, 2, 0, nullptr, nullptr, nullptr, bg, ZR, nullptr, nullptr);

    // update phase
    build_t2<<<512, 256, 0, stream>>>(x, st, ZR, T0);
    gemm_pipe<<<528, 256, 0, stream>>>(S, 2048, T0, 2048, 2048, 0, 1, T1, nullptr, nullptr, nullptr, nullptr, nullptr, nullptr);
    gemm_pipe<<<528, 256, 0, stream>>>(S, 2048, T1, 2048, 2048, 1, 1, T2, T0, nullptr, nullptr, nullptr, nullptr, nullptr);
    transpose_g<<<512, 256, 0, stream>>>(T0, T1, T2, G);
    gemm_pipe<<<dim3(512, 1), 256, 0, stream>>>(G, 256, WTu, 256, 256, 3, 0, nullptr, nullptr, out, bu, nullptr, ZR, st);
}